// Round 2
// baseline (421.411 us; speedup 1.0000x reference)
//
#include <hip/hip_runtime.h>
#include <math.h>

#define BATCH    65536
#define FEAT     512
#define NCLASS   16
#define LAMDA    1.0f
#define LAMDA1   10.0f
#define SCALE    1.0f
#define EPS      1e-9f

// Launch geometry: compile-time so the main loop fully unrolls.
constexpr int BLOCK  = 256;
constexpr int GRID   = 4096;
constexpr int NV     = BATCH * (FEAT / 4);     // 8,388,608 float4 elements
constexpr int STRIDE = GRID * BLOCK;           // 1,048,576
constexpr int ITERS  = NV / STRIDE;            // exactly 8

// ws layout: ws[0] = accum (float), ws[1] = block-completion counter (uint)
// Single fused kernel:
//  - all blocks: unrolled center-loss partial sum -> wave shuffle reduce ->
//    LDS reduce -> one device-scope atomicAdd per block
//  - last block to finish (atomic ticket): computes the 16x16 gram directly
//    from L2-hot centers, the 120-pair upper-triangle cosine sum, and writes
//    the final scalar.
__global__ __launch_bounds__(BLOCK) void island_loss_fused(
    const float4* __restrict__ x,        // [BATCH * FEAT/4]
    const int*    __restrict__ y,        // [BATCH]
    const float4* __restrict__ centers4, // [NCLASS * FEAT/4]
    float*        __restrict__ accum,    // ws[0], pre-zeroed
    unsigned int* __restrict__ counter,  // ws[1], pre-zeroed
    float*        __restrict__ out)      // [1]
{
    const int tid = blockIdx.x * BLOCK + threadIdx.x;

    // b = i >> 7 is wave-uniform: a wave spans 64 consecutive i inside one
    // 128-aligned chunk, and STRIDE is a multiple of 128. Force it scalar so
    // y[b] becomes an s_load and the center loads get an SGPR base.
    const int base_b = __builtin_amdgcn_readfirstlane(tid >> 7);
    const int d4     = tid & 127;

    float sum = 0.0f;
    #pragma unroll
    for (int it = 0; it < ITERS; ++it) {
        const int i = tid + it * STRIDE;
        float4 xv = x[i];
        int cls = y[base_b + it * (STRIDE >> 7)];
        float4 cv = centers4[cls * (FEAT / 4) + d4];
        float e0 = xv.x - cv.x;
        float e1 = xv.y - cv.y;
        float e2 = xv.z - cv.z;
        float e3 = xv.w - cv.w;
        sum += e0 * e0 + e1 * e1 + e2 * e2 + e3 * e3;
    }

    // wave (64-lane) shuffle reduction
    #pragma unroll
    for (int off = 32; off > 0; off >>= 1)
        sum += __shfl_down(sum, off, 64);

    __shared__ float wsum[4];
    __shared__ int   is_last;
    const int lane = threadIdx.x & 63;
    const int wid  = threadIdx.x >> 6;
    if (lane == 0) wsum[wid] = sum;
    __syncthreads();
    if (threadIdx.x == 0) {
        float s = wsum[0] + wsum[1] + wsum[2] + wsum[3];
        atomicAdd(accum, s);                 // device-scope by default
        __threadfence();
        unsigned old = atomicAdd(counter, 1u);
        is_last = (old == (unsigned)(GRID - 1)) ? 1 : 0;
    }
    __syncthreads();

    if (is_last) {
        // ---- pairwise cosine over centers (16x16 gram from L2-hot data) ----
        __shared__ float gram[NCLASS][NCLASS];
        const int j = threadIdx.x >> 4;
        const int k = threadIdx.x & 15;
        const float4* cj = centers4 + j * (FEAT / 4);
        const float4* ck = centers4 + k * (FEAT / 4);
        float dot = 0.0f;
        #pragma unroll 8
        for (int i = 0; i < FEAT / 4; ++i) {
            float4 a = cj[i];
            float4 b = ck[i];
            dot += a.x * b.x + a.y * b.y + a.z * b.z + a.w * b.w;
        }
        gram[j][k] = dot;
        __syncthreads();

        if (threadIdx.x == 0) {
            float item1 = 0.0f;
            for (int jj = 0; jj < NCLASS; ++jj) {
                float nj = sqrtf(gram[jj][jj]);
                for (int kk = jj + 1; kk < NCLASS; ++kk) {
                    float nk = sqrtf(gram[kk][kk]);
                    item1 += gram[jj][kk] / (nj * nk + EPS) + 1.0f;
                }
            }
            __threadfence();
            float total = atomicAdd(accum, 0.0f);  // coherent device-scope read
            float loss_center = 0.5f * total * (SCALE / (float)BATCH);
            out[0] = LAMDA * (loss_center + LAMDA1 * item1);
        }
    }
}

extern "C" void kernel_launch(void* const* d_in, const int* in_sizes, int n_in,
                              void* d_out, int out_size, void* d_ws, size_t ws_size,
                              hipStream_t stream) {
    const float* x       = (const float*)d_in[0];   // [BATCH, FEAT]
    const int*   y       = (const int*)d_in[1];     // [BATCH]
    const float* centers = (const float*)d_in[2];   // [NCLASS, FEAT]
    float* out = (float*)d_out;

    float*        accum   = (float*)d_ws;
    unsigned int* counter = (unsigned int*)((char*)d_ws + sizeof(float));

    hipMemsetAsync(d_ws, 0, 2 * sizeof(float), stream);

    island_loss_fused<<<GRID, BLOCK, 0, stream>>>(
        (const float4*)x, y, (const float4*)centers, accum, counter, out);
}

// Round 3
// 232.227 us; speedup vs baseline: 1.8147x; 1.8147x over previous
//
#include <hip/hip_runtime.h>
#include <math.h>

#define BATCH    65536
#define FEAT     512
#define NCLASS   16
#define LAMDA    1.0f
#define LAMDA1   10.0f
#define SCALE    1.0f
#define EPS      1e-9f

// Compile-time launch geometry so the main loop fully unrolls:
// 8 independent global_load_dwordx4 in flight per wave (round-1 kernel had
// VGPR_Count=8 => fully serial dependent loads => 80 us latency-bound).
constexpr int BLOCK  = 256;
constexpr int GRID   = 4096;
constexpr int NV     = BATCH * (FEAT / 4);     // 8,388,608 float4 elements
constexpr int STRIDE = GRID * BLOCK;           // 1,048,576
constexpr int ITERS  = NV / STRIDE;            // exactly 8

// ---------------------------------------------------------------------------
// Kernel 1: center-loss partial sums. NO fences (round-2 lesson: per-block
// device-scope __threadfence costs ~L2 writeback each => 3.5x regression).
// Cross-kernel visibility comes free from the kernel boundary.
// ---------------------------------------------------------------------------
__global__ __launch_bounds__(BLOCK) void center_loss_kernel(
    const float4* __restrict__ x,        // [BATCH * FEAT/4]
    const int*    __restrict__ y,        // [BATCH]
    const float4* __restrict__ centers4, // [NCLASS * FEAT/4]
    float*        __restrict__ accum)    // ws[0], pre-zeroed
{
    const int tid = blockIdx.x * BLOCK + threadIdx.x;

    // b = i>>7 is wave-uniform (wave = 64 consecutive i inside one 128-aligned
    // chunk; STRIDE % 128 == 0). readfirstlane -> y loads become s_load.
    const int base_b = __builtin_amdgcn_readfirstlane(tid >> 7);
    const int d4     = tid & 127;

    float sum = 0.0f;
    #pragma unroll
    for (int it = 0; it < ITERS; ++it) {
        const int i = tid + it * STRIDE;
        float4 xv = x[i];
        int cls = y[base_b + it * (STRIDE >> 7)];
        float4 cv = centers4[cls * (FEAT / 4) + d4];
        float e0 = xv.x - cv.x;
        float e1 = xv.y - cv.y;
        float e2 = xv.z - cv.z;
        float e3 = xv.w - cv.w;
        sum += e0 * e0 + e1 * e1 + e2 * e2 + e3 * e3;
    }

    // wave (64-lane) shuffle reduction
    #pragma unroll
    for (int off = 32; off > 0; off >>= 1)
        sum += __shfl_down(sum, off, 64);

    __shared__ float wsum[4];
    const int lane = threadIdx.x & 63;
    const int wid  = threadIdx.x >> 6;
    if (lane == 0) wsum[wid] = sum;
    __syncthreads();
    if (threadIdx.x == 0) {
        atomicAdd(accum, wsum[0] + wsum[1] + wsum[2] + wsum[3]);
    }
}

// ---------------------------------------------------------------------------
// Kernel 2 (single block): 16x16 gram from L2-hot centers + final combine.
// ---------------------------------------------------------------------------
__global__ __launch_bounds__(256) void finalize_kernel(
    const float4* __restrict__ centers4, // [NCLASS * FEAT/4]
    const float*  __restrict__ accum,    // ws[0]
    float*        __restrict__ out)      // [1]
{
    __shared__ float gram[NCLASS][NCLASS];
    const int j = threadIdx.x >> 4;
    const int k = threadIdx.x & 15;
    const float4* cj = centers4 + j * (FEAT / 4);
    const float4* ck = centers4 + k * (FEAT / 4);
    float dot = 0.0f;
    #pragma unroll 8
    for (int i = 0; i < FEAT / 4; ++i) {
        float4 a = cj[i];
        float4 b = ck[i];
        dot += a.x * b.x + a.y * b.y + a.z * b.z + a.w * b.w;
    }
    gram[j][k] = dot;
    __syncthreads();

    if (threadIdx.x == 0) {
        float item1 = 0.0f;
        for (int jj = 0; jj < NCLASS; ++jj) {
            float nj = sqrtf(gram[jj][jj]);
            for (int kk = jj + 1; kk < NCLASS; ++kk) {
                float nk = sqrtf(gram[kk][kk]);
                item1 += gram[jj][kk] / (nj * nk + EPS) + 1.0f;
            }
        }
        float loss_center = 0.5f * accum[0] * (SCALE / (float)BATCH);
        out[0] = LAMDA * (loss_center + LAMDA1 * item1);
    }
}

extern "C" void kernel_launch(void* const* d_in, const int* in_sizes, int n_in,
                              void* d_out, int out_size, void* d_ws, size_t ws_size,
                              hipStream_t stream) {
    const float* x       = (const float*)d_in[0];   // [BATCH, FEAT]
    const int*   y       = (const int*)d_in[1];     // [BATCH]
    const float* centers = (const float*)d_in[2];   // [NCLASS, FEAT]
    float* out   = (float*)d_out;
    float* accum = (float*)d_ws;

    hipMemsetAsync(accum, 0, sizeof(float), stream);

    center_loss_kernel<<<GRID, BLOCK, 0, stream>>>(
        (const float4*)x, y, (const float4*)centers, accum);

    finalize_kernel<<<1, 256, 0, stream>>>((const float4*)centers, accum, out);
}